// Round 1
// baseline (279.939 us; speedup 1.0000x reference)
//
#include <hip/hip_runtime.h>

#define NCOLS 256
#define NP    128
#define DD    256

typedef _Float16 half8  __attribute__((ext_vector_type(8)));
typedef _Float16 half4v __attribute__((ext_vector_type(4)));
typedef float    f32x4  __attribute__((ext_vector_type(4)));

// ---- workspace layout (bytes) ----
#define WS_COL_LN   0          // f32 [256][256]  LN(emb_column)
#define WS_LNP      262144     // f32 [128][256]  LN(emb_prompt)
#define WS_BASE     393216     // f32 [128][256]  base (prompt-side xp part)
#define WS_BLOG     524288     // f32 [128][256]  base_logits
#define WS_CW16     655360     // f16 [256][256]  CW = col_ln @ W2
#define WS_W16      786432     // f16 [256][256]  feature_emb_weight
#define WS_B16      917504     // f16 [256][256]  feature_emb_bias

// ---- main-kernel LDS layout (bytes) ----
#define MSK_STRIDE 264
#define XE_STRIDE  68
#define CW_STRIDE  40
#define MASK_OFF 3072
#define XE0_OFF  70656
#define R2_OFF   105472          // union: CW stage dbuf (40960) / xe buf1 (34816)
#define SMEM_BYTES 146432

// ============================ stage 0 kernels ============================

// blocks 0..255: LN rows of emb_column; 256..383: LN rows of emb_prompt;
// 384..511: f16 casts of feature_emb_weight / bias.
__global__ __launch_bounds__(256) void k0a(
    const float* __restrict__ emb_column, const float* __restrict__ emb_prompt,
    const float* __restrict__ ln_col_g, const float* __restrict__ ln_col_b,
    const float* __restrict__ ln_prompt_g, const float* __restrict__ ln_prompt_b,
    const float* __restrict__ few, const float* __restrict__ feb, char* __restrict__ ws)
{
    __shared__ float red[10];
    int blk = blockIdx.x, tid = threadIdx.x;
    if (blk < 384) {
        const float *src, *g, *bb; float* dst;
        if (blk < 256) { int r = blk;   src = emb_column + r*DD; g = ln_col_g;    bb = ln_col_b;    dst = (float*)(ws + WS_COL_LN) + r*DD; }
        else           { int r = blk-256; src = emb_prompt + r*DD; g = ln_prompt_g; bb = ln_prompt_b; dst = (float*)(ws + WS_LNP) + r*DD; }
        float v = src[tid];
        float s = v, q = v*v;
        #pragma unroll
        for (int off = 32; off; off >>= 1) { s += __shfl_xor(s, off); q += __shfl_xor(q, off); }
        int wid = tid >> 6, lane = tid & 63;
        if (lane == 0) { red[wid] = s; red[4+wid] = q; }
        __syncthreads();
        if (tid == 0) {
            float S = red[0]+red[1]+red[2]+red[3];
            float Q = red[4]+red[5]+red[6]+red[7];
            float mu = S * (1.0f/DD);
            float var = Q * (1.0f/DD) - mu*mu;
            red[8] = mu; red[9] = rsqrtf(var + 1e-5f);
        }
        __syncthreads();
        dst[tid] = (v - red[8]) * red[9] * g[tid] + bb[tid];
    } else {
        int base = (blk - 384) * 1024;
        _Float16* w16 = (_Float16*)(ws + WS_W16);
        _Float16* b16 = (_Float16*)(ws + WS_B16);
        #pragma unroll
        for (int j = 0; j < 4; ++j) {
            int idx = base + j*256 + tid;
            if (idx < 65536) w16[idx] = (_Float16)few[idx];
            else             b16[idx - 65536] = (_Float16)feb[idx - 65536];
        }
    }
}

// blocks 0..255: CW[n][k] = sum_d col_ln[n][d] * diw[d][256+k]  (f16)
// blocks 256..383: base[p][d] = sum_k LNp[p][k]*diw[d][k] + dib[d] + emb_prompt[p][d]
__global__ __launch_bounds__(256) void k0b(
    const float* __restrict__ diw, const float* __restrict__ dib,
    const float* __restrict__ emb_prompt, char* __restrict__ ws)
{
    __shared__ float rowv[DD];
    int blk = blockIdx.x, tid = threadIdx.x;
    if (blk < 256) {
        int n = blk;
        const float* col_ln = (const float*)(ws + WS_COL_LN);
        rowv[tid] = col_ln[n*DD + tid];
        __syncthreads();
        float acc = 0.f;
        #pragma unroll 4
        for (int d = 0; d < DD; ++d) acc += rowv[d] * diw[d*512 + 256 + tid];
        ((_Float16*)(ws + WS_CW16))[n*DD + tid] = (_Float16)acc;
    } else {
        int p = blk - 256;
        const float* lnp = (const float*)(ws + WS_LNP);
        rowv[tid] = lnp[p*DD + tid];
        __syncthreads();
        float acc = 0.f;
        #pragma unroll 4
        for (int k = 0; k < DD; ++k) acc += rowv[k] * diw[tid*512 + k];
        ((float*)(ws + WS_BASE))[p*DD + tid] = acc + dib[tid] + emb_prompt[p*DD + tid];
    }
}

// base_logits[p][n] = sum_d base[p][d] * col_ln[n][d]
__global__ __launch_bounds__(256) void k0c(char* __restrict__ ws)
{
    __shared__ float bs[DD];
    int p = blockIdx.x, n = threadIdx.x;
    const float* base   = (const float*)(ws + WS_BASE);
    const float* col_ln = (const float*)(ws + WS_COL_LN);
    bs[n] = base[p*DD + n];
    __syncthreads();
    float acc = 0.f;
    #pragma unroll 4
    for (int d = 0; d < DD; ++d) acc += bs[d] * col_ln[n*DD + d];
    ((float*)(ws + WS_BLOG))[p*DD + n] = acc;
}

// ============================ main kernel ============================
// 1 block = 1 batch element. 8 waves.
// P1: logits^T tiles via mfma(CW, prev^T): D[n][p], wave w owns p in [16w,16w+16)
// P2: softmax per lane (lane lr holds full row p=16w+lr), write normalized P (f16) to LDS
// P3: PV = P @ x_emb with x_emb computed on the fly into transposed LDS tiles (dbuf)
__global__ __launch_bounds__(512, 2) void trompt_main(
    const float* __restrict__ x, const float* __restrict__ prev,
    const float* __restrict__ expand_w, const float* __restrict__ expand_b,
    const float* __restrict__ ln_emb_g, const float* __restrict__ ln_emb_b,
    const char* __restrict__ ws, float* __restrict__ out)
{
    extern __shared__ char smem[];
    float* x_s  = (float*)(smem);
    float* g_s  = (float*)(smem + 1024);
    float* bb_s = (float*)(smem + 2048);
    _Float16* mask_s = (_Float16*)(smem + MASK_OFF);
    _Float16* xe0    = (_Float16*)(smem + XE0_OFF);
    _Float16* cwst   = (_Float16*)(smem + R2_OFF);
    _Float16* xe1    = (_Float16*)(smem + R2_OFF);

    const _Float16* CW16 = (const _Float16*)(ws + WS_CW16);
    const _Float16* W16  = (const _Float16*)(ws + WS_W16);
    const _Float16* B16  = (const _Float16*)(ws + WS_B16);
    const float*    blog = (const float*)(ws + WS_BLOG);

    int b = blockIdx.x;
    int tid = threadIdx.x;
    int w = tid >> 6, l = tid & 63, lq = l >> 4, lr = l & 15;

    if (tid < 256) {
        x_s[tid]  = x[b*NCOLS + tid];
        g_s[tid]  = ln_emb_g[tid];
        bb_s[tid] = ln_emb_b[tid];
    }
    __syncthreads();

    // x_emb tile compute: 8 rows per wave; lane handles d = l + 64c (conflict-free
    // transposed stores: bank = 2*l mod 32, 2-way). LN in f32.
    auto compute_xe = [&](int tile, _Float16* xb) {
        #pragma unroll 2
        for (int i = 0; i < 8; ++i) {
            int nloc = w + 8*i;
            int n = tile*64 + nloc;
            float xv = x_s[n];
            float ev[4]; float s = 0.f, q = 0.f;
            #pragma unroll
            for (int c = 0; c < 4; ++c) {
                int d = l + 64*c;
                float wv = (float)W16[n*DD + d];
                float bv = (float)B16[n*DD + d];
                float e = xv*wv + bv;
                e = e > 0.f ? e : 0.f;
                ev[c] = e; s += e; q += e*e;
            }
            #pragma unroll
            for (int off = 32; off; off >>= 1) { s += __shfl_xor(s, off); q += __shfl_xor(q, off); }
            float mu = s * (1.0f/DD);
            float rs = rsqrtf(q*(1.0f/DD) - mu*mu + 1e-5f);
            #pragma unroll
            for (int c = 0; c < 4; ++c) {
                int d = l + 64*c;
                xb[d*XE_STRIDE + nloc] = (_Float16)((ev[c]-mu)*rs*g_s[d] + bb_s[d]);
            }
        }
    };

    // prologue: stage CW k-slice 0 into buf0, compute x_emb tile 0 into xe0
    {
        #pragma unroll
        for (int i = 0; i < 2; ++i) {
            int c = tid + 512*i;
            int row = c >> 2, kc = c & 3;
            f32x4 v = *(const f32x4*)((const char*)CW16 + row*512 + kc*16);
            *(f32x4*)((char*)cwst + row*(CW_STRIDE*2) + kc*16) = v;
        }
        compute_xe(0, xe0);
    }
    __syncthreads();

    // ---------------- P1: logits^T = CW @ prev^T + base_logits ----------------
    f32x4 acc_l[16];
    #pragma unroll
    for (int nt = 0; nt < 16; ++nt) acc_l[nt] = (f32x4){0.f,0.f,0.f,0.f};

    const float* prow = prev + ((size_t)b*NP + 16*w + lr) * DD;
    f32x4 pa0 = *(const f32x4*)(prow + lq*8);
    f32x4 pa1 = *(const f32x4*)(prow + lq*8 + 4);

    for (int kk = 0; kk < 8; ++kk) {
        _Float16* cw_cur = cwst + (kk & 1) * (256*CW_STRIDE);
        _Float16* cw_nxt = cwst + ((kk+1) & 1) * (256*CW_STRIDE);
        // issue next-slice staging loads early (write after MFMAs)
        f32x4 s0{}, s1{};
        if (kk < 7) {
            int k0n = (kk+1) * 32;
            int c0 = tid, c1 = tid + 512;
            s0 = *(const f32x4*)((const char*)CW16 + (c0>>2)*512 + k0n*2 + (c0&3)*16);
            s1 = *(const f32x4*)((const char*)CW16 + (c1>>2)*512 + k0n*2 + (c1&3)*16);
        }
        // B fragment: prev^T, lane col p=16w+lr, k = kk*32 + 8lq + j
        half8 a;
        #pragma unroll
        for (int j = 0; j < 4; ++j) { a[j] = (_Float16)pa0[j]; a[4+j] = (_Float16)pa1[j]; }
        if (kk < 7) {
            pa0 = *(const f32x4*)(prow + (kk+1)*32 + lq*8);
            pa1 = *(const f32x4*)(prow + (kk+1)*32 + lq*8 + 4);
        }
        #pragma unroll
        for (int nt = 0; nt < 16; ++nt) {
            half8 cw = *(const half8*)(cw_cur + (16*nt + lr)*CW_STRIDE + lq*8);
            acc_l[nt] = __builtin_amdgcn_mfma_f32_16x16x32_f16(cw, a, acc_l[nt], 0, 0, 0);
        }
        if (kk < 7) {
            int c0 = tid, c1 = tid + 512;
            *(f32x4*)((char*)cw_nxt + (c0>>2)*(CW_STRIDE*2) + (c0&3)*16) = s0;
            *(f32x4*)((char*)cw_nxt + (c1>>2)*(CW_STRIDE*2) + (c1&3)*16) = s1;
        }
        __syncthreads();
    }

    // add base_logits: lane holds (n = 16nt+4lq+r, p = 16w+lr)
    #pragma unroll
    for (int nt = 0; nt < 16; ++nt) {
        f32x4 bl = *(const f32x4*)(blog + (16*w + lr)*DD + 16*nt + 4*lq);
        acc_l[nt] += bl;
    }

    // ---------------- P2: softmax over n (rows are lane-local + 2 shfl) ----------------
    float mx = -1e30f;
    #pragma unroll
    for (int nt = 0; nt < 16; ++nt)
        #pragma unroll
        for (int r = 0; r < 4; ++r) mx = fmaxf(mx, acc_l[nt][r]);
    mx = fmaxf(mx, __shfl_xor(mx, 16));
    mx = fmaxf(mx, __shfl_xor(mx, 32));
    float sum = 0.f;
    #pragma unroll
    for (int nt = 0; nt < 16; ++nt)
        #pragma unroll
        for (int r = 0; r < 4; ++r) { float e = __expf(acc_l[nt][r] - mx); acc_l[nt][r] = e; sum += e; }
    sum += __shfl_xor(sum, 16);
    sum += __shfl_xor(sum, 32);
    float inv = 1.0f / sum;
    #pragma unroll
    for (int nt = 0; nt < 16; ++nt) {
        half4v m4;
        #pragma unroll
        for (int r = 0; r < 4; ++r) m4[r] = (_Float16)(acc_l[nt][r] * inv);
        *(half4v*)(mask_s + (16*w + lr)*MSK_STRIDE + 16*nt + 4*lq) = m4;
    }
    __syncthreads();

    // ---------------- P3: V = P @ x_emb (x_emb tiles dbuf'd against MFMA) ----------------
    f32x4 acc_v[16];
    #pragma unroll
    for (int dt = 0; dt < 16; ++dt) acc_v[dt] = (f32x4){0.f,0.f,0.f,0.f};

    for (int t = 0; t < 4; ++t) {
        _Float16* xb = (t & 1) ? xe1 : xe0;
        if (t < 3) compute_xe(t+1, (t & 1) ? xe0 : xe1);
        #pragma unroll
        for (int ks2 = 0; ks2 < 2; ++ks2) {
            int ks = 2*t + ks2;
            half8 a = *(const half8*)(mask_s + (16*w + lr)*MSK_STRIDE + 32*ks + 8*lq);
            #pragma unroll
            for (int dt = 0; dt < 16; ++dt) {
                const _Float16* bp = xb + (16*dt + lr)*XE_STRIDE + 32*ks2 + 8*lq;
                half4v b0 = *(const half4v*)(bp);
                half4v b1 = *(const half4v*)(bp + 4);
                half8 bf;
                #pragma unroll
                for (int j = 0; j < 4; ++j) { bf[j] = b0[j]; bf[4+j] = b1[j]; }
                acc_v[dt] = __builtin_amdgcn_mfma_f32_16x16x32_f16(a, bf, acc_v[dt], 0, 0, 0);
            }
        }
        __syncthreads();
    }

    // epilogue: out = V*(1+expand_w[p]) + expand_b[p]; lane rows p = 16w+4lq+r, col d=16dt+lr
    int p0 = 16*w + 4*lq;
    float sw_[4], sb_[4];
    #pragma unroll
    for (int r = 0; r < 4; ++r) { sw_[r] = 1.0f + expand_w[p0 + r]; sb_[r] = expand_b[p0 + r]; }
    #pragma unroll
    for (int dt = 0; dt < 16; ++dt)
        #pragma unroll
        for (int r = 0; r < 4; ++r)
            out[((size_t)b*NP + p0 + r)*DD + 16*dt + lr] = acc_v[dt][r]*sw_[r] + sb_[r];
}

// ============================ launcher ============================
extern "C" void kernel_launch(void* const* d_in, const int* in_sizes, int n_in,
                              void* d_out, int out_size, void* d_ws, size_t ws_size,
                              hipStream_t stream) {
    (void)in_sizes; (void)n_in; (void)out_size; (void)ws_size;
    const float* x           = (const float*)d_in[0];
    const float* prev        = (const float*)d_in[1];
    const float* few         = (const float*)d_in[2];
    const float* feb         = (const float*)d_in[3];
    const float* ln_emb_g    = (const float*)d_in[4];
    const float* ln_emb_b    = (const float*)d_in[5];
    const float* ln_col_g    = (const float*)d_in[6];
    const float* ln_col_b    = (const float*)d_in[7];
    const float* ln_prompt_g = (const float*)d_in[8];
    const float* ln_prompt_b = (const float*)d_in[9];
    const float* diw         = (const float*)d_in[10];
    const float* dib         = (const float*)d_in[11];
    const float* emb_column  = (const float*)d_in[12];
    const float* emb_prompt  = (const float*)d_in[13];
    const float* expand_w    = (const float*)d_in[14];
    const float* expand_b    = (const float*)d_in[15];
    char* ws = (char*)d_ws;
    float* out = (float*)d_out;

    k0a<<<512, 256, 0, stream>>>(emb_column, emb_prompt, ln_col_g, ln_col_b,
                                 ln_prompt_g, ln_prompt_b, few, feb, ws);
    k0b<<<384, 256, 0, stream>>>(diw, dib, emb_prompt, ws);
    k0c<<<128, 256, 0, stream>>>(ws);

    (void)hipFuncSetAttribute(reinterpret_cast<const void*>(trompt_main),
                              hipFuncAttributeMaxDynamicSharedMemorySize, SMEM_BYTES);
    trompt_main<<<1024, 512, SMEM_BYTES, stream>>>(x, prev, expand_w, expand_b,
                                                   ln_emb_g, ln_emb_b, ws, out);
}